// Round 1
// baseline (5007.800 us; speedup 1.0000x reference)
//
#include <hip/hip_runtime.h>
#include <math.h>

// Problem constants
#define DIMX   1024
#define NHEADS 16
#define HD     64
#define BATCH  4
#define SEQ    2048
#define NM     (BATCH * NHEADS * SEQ * HD)   // 8388608 elements per Q/K/V tensor

// ---------------------------------------------------------------------------
// Kernel 1: QKV projection.  out[b][n][l][e] = sum_d x[b][l][d] * w[n][d][e]
// Treated as 48 GEMMs (3 matrices x 16 heads), M=8192, N=64, K=1024.
// 64x64 output tile per block, K-chunk 32, X staged TRANSPOSED in LDS so the
// inner loop is 2x ds_read_b128 + 16 fp32 FMA per k-step (VALU-bound).
// ---------------------------------------------------------------------------
__global__ __launch_bounds__(256) void qkv_proj_kernel(
    const float* __restrict__ x,
    const float* __restrict__ wk,
    const float* __restrict__ wq,
    const float* __restrict__ wv,
    float* __restrict__ Qf, float* __restrict__ Kf, float* __restrict__ Vf)
{
    __shared__ float Xs[32][68];   // [k][row]  (transposed; pad 68 keeps b128 rows aligned)
    __shared__ float Ws[32][68];   // [k][col]

    const int mtile = blockIdx.x;        // 0..127 -> rows mtile*64 .. +63
    const int y     = blockIdx.y;        // 0..47
    const int head  = y & 15;
    const int which = y >> 4;            // 0: wk->K, 1: wq->Q, 2: wv->V
    const float* w    = (which == 0) ? wk : (which == 1) ? wq : wv;
    float*       outp = (which == 0) ? Kf : (which == 1) ? Qf : Vf;
    const float* wb = w + (size_t)head * (DIMX * HD);

    const int tid = threadIdx.x;
    const int tr  = tid >> 4;    // 0..15 (row group)
    const int tc  = tid & 15;    // 0..15 (col group)
    const int row0 = mtile * 64;

    float acc[4][4] = {{0.f,0.f,0.f,0.f},{0.f,0.f,0.f,0.f},
                       {0.f,0.f,0.f,0.f},{0.f,0.f,0.f,0.f}};

    for (int kc = 0; kc < DIMX; kc += 32) {
        __syncthreads();
        // Stage X chunk (64 rows x 32 k), transposed into Xs[k][row]. Coalesced reads.
        #pragma unroll
        for (int t = 0; t < 8; t++) {
            int i = tid + t * 256;
            int r = i >> 5, c = i & 31;
            Xs[c][r] = x[(size_t)(row0 + r) * DIMX + kc + c];
        }
        // Stage W chunk (32 k x 64 cols). Coalesced reads.
        #pragma unroll
        for (int t = 0; t < 8; t++) {
            int i = tid + t * 256;
            int r = i >> 6, c = i & 63;
            Ws[r][c] = wb[(size_t)(kc + r) * HD + c];
        }
        __syncthreads();
        #pragma unroll
        for (int kk = 0; kk < 32; kk++) {
            float4 a = *(const float4*)&Xs[kk][tr * 4];
            float4 b = *(const float4*)&Ws[kk][tc * 4];
            acc[0][0] += a.x*b.x; acc[0][1] += a.x*b.y; acc[0][2] += a.x*b.z; acc[0][3] += a.x*b.w;
            acc[1][0] += a.y*b.x; acc[1][1] += a.y*b.y; acc[1][2] += a.y*b.z; acc[1][3] += a.y*b.w;
            acc[2][0] += a.z*b.x; acc[2][1] += a.z*b.y; acc[2][2] += a.z*b.z; acc[2][3] += a.z*b.w;
            acc[3][0] += a.w*b.x; acc[3][1] += a.w*b.y; acc[3][2] += a.w*b.z; acc[3][3] += a.w*b.w;
        }
    }
    // Write 4x4 micro-tile. Layout: [b][n][l][e], contiguous float4 along e.
    #pragma unroll
    for (int i = 0; i < 4; i++) {
        int m = row0 + tr * 4 + i;       // global row in [0, 8192)
        int b = m >> 11;                 // / 2048
        int l = m & 2047;
        float4 v = make_float4(acc[i][0], acc[i][1], acc[i][2], acc[i][3]);
        *(float4*)&outp[(((size_t)b * NHEADS + head) * SEQ + l) * HD + tc * 4] = v;
    }
}

// ---------------------------------------------------------------------------
// Kernel 2: flash attention (online softmax), fp32.
// Block = 256 threads (4 waves), handles one (b,n) and 64 query rows.
// Loops 32 chunks of 64 keys: stage K[64][64] and V transposed Vt[e][j] in LDS.
// Each wave owns 16 rows; rows processed in groups of 4 so each Ks/Vt b128
// read feeds 4 rows' FMAs (Q and P reads are same-address broadcasts).
// Phase A: lane = key j -> score s_j. Phase B: lane = dim e -> O accumulation.
// ---------------------------------------------------------------------------
__global__ __launch_bounds__(256) void attn_kernel(
    const float* __restrict__ Qf, const float* __restrict__ Kf,
    const float* __restrict__ Vf, float* __restrict__ out)
{
    __shared__ float Qs[64][64];      // q rows, pre-scaled by 1/8
    __shared__ float Ks[64][68];      // [j][e]
    __shared__ float Vt[64][68];      // [e][j]  (transposed)
    __shared__ float Os[64][64];      // output accumulator [row][e]
    __shared__ float Ps[4][4][64];    // per-wave, per-rowgroup p vector
    __shared__ float Ms[64];          // running max per row
    __shared__ float Ls[64];          // running denom per row

    const int qt  = blockIdx.x;       // 0..31 (query tile)
    const int bn  = blockIdx.y;       // 0..63 (b*16+n)
    const int tid = threadIdx.x;
    const int wave = tid >> 6;
    const int lane = tid & 63;
    const float* Qb = Qf + (size_t)bn * SEQ * HD;
    const float* Kb = Kf + (size_t)bn * SEQ * HD;
    const float* Vb = Vf + (size_t)bn * SEQ * HD;

    // Load Q tile (64x64), scale by 1/sqrt(64) = 0.125.
    #pragma unroll
    for (int t = 0; t < 4; t++) {
        int i4 = tid + t * 256;                  // 0..1023 float4-slots
        int r = i4 >> 4, c = (i4 & 15) * 4;
        float4 q = *(const float4*)&Qb[(size_t)(qt * 64 + r) * HD + c];
        q.x *= 0.125f; q.y *= 0.125f; q.z *= 0.125f; q.w *= 0.125f;
        *(float4*)&Qs[r][c] = q;
    }
    #pragma unroll
    for (int t = 0; t < 16; t++) ((float*)Os)[tid + t * 256] = 0.f;
    if (tid < 64) { Ms[tid] = -1e30f; Ls[tid] = 0.f; }

    for (int ch = 0; ch < 32; ch++) {
        __syncthreads();   // prev iteration's compute done before overwriting tiles
        #pragma unroll
        for (int t = 0; t < 4; t++) {
            int i4 = tid + t * 256;
            int r = i4 >> 4, c = (i4 & 15) * 4;
            float4 kv = *(const float4*)&Kb[(size_t)(ch * 64 + r) * HD + c];
            *(float4*)&Ks[r][c] = kv;
            float4 vv = *(const float4*)&Vb[(size_t)(ch * 64 + r) * HD + c];
            Vt[c + 0][r] = vv.x; Vt[c + 1][r] = vv.y;
            Vt[c + 2][r] = vv.z; Vt[c + 3][r] = vv.w;
        }
        __syncthreads();

        #pragma unroll 1
        for (int rg = 0; rg < 16; rg += 4) {
            const int row0 = wave * 16 + rg;
            // ---- Phase A: lane = key index j; scores for 4 rows sharing K reads
            float s[4] = {0.f, 0.f, 0.f, 0.f};
            #pragma unroll
            for (int e = 0; e < 64; e += 4) {
                float4 k = *(const float4*)&Ks[lane][e];
                #pragma unroll
                for (int g = 0; g < 4; g++) {
                    float4 q = *(const float4*)&Qs[row0 + g][e];  // broadcast
                    s[g] += q.x*k.x + q.y*k.y + q.z*k.z + q.w*k.w;
                }
            }
            float alpha[4];
            #pragma unroll
            for (int g = 0; g < 4; g++) {
                float mx = s[g];
                #pragma unroll
                for (int d = 1; d < 64; d <<= 1) mx = fmaxf(mx, __shfl_xor(mx, d));
                float mo = Ms[row0 + g];                 // broadcast read
                float mn = fmaxf(mo, mx);
                float p  = __expf(s[g] - mn);
                float su = p;
                #pragma unroll
                for (int d = 1; d < 64; d <<= 1) su += __shfl_xor(su, d);
                alpha[g] = __expf(mo - mn);
                if (lane == 0) { Ms[row0 + g] = mn; Ls[row0 + g] = Ls[row0 + g] * alpha[g] + su; }
                Ps[wave][g][lane] = p;
            }
            // ---- Phase B: lane = dim e; O update for 4 rows sharing V reads
            float o[4] = {0.f, 0.f, 0.f, 0.f};
            #pragma unroll
            for (int j = 0; j < 64; j += 4) {
                float4 vv = *(const float4*)&Vt[lane][j];
                #pragma unroll
                for (int g = 0; g < 4; g++) {
                    float4 p4 = *(const float4*)&Ps[wave][g][j];  // broadcast
                    o[g] += p4.x*vv.x + p4.y*vv.y + p4.z*vv.z + p4.w*vv.w;
                }
            }
            #pragma unroll
            for (int g = 0; g < 4; g++)
                Os[row0 + g][lane] = Os[row0 + g][lane] * alpha[g] + o[g];
        }
    }

    // Epilogue: out[b][l][n*64+e] = O / L. Rows are wave-exclusive; lane = e.
    const int b = bn >> 4, n = bn & 15;
    #pragma unroll 1
    for (int r = 0; r < 16; r++) {
        int row = wave * 16 + r;
        int l = qt * 64 + row;
        out[((size_t)(b * SEQ + l)) * (NHEADS * HD) + n * HD + lane] = Os[row][lane] / Ls[row];
    }
}

// ---------------------------------------------------------------------------
extern "C" void kernel_launch(void* const* d_in, const int* in_sizes, int n_in,
                              void* d_out, int out_size, void* d_ws, size_t ws_size,
                              hipStream_t stream) {
    const float* x  = (const float*)d_in[0];
    const float* wk = (const float*)d_in[1];
    const float* wq = (const float*)d_in[2];
    const float* wv = (const float*)d_in[3];
    float* out = (float*)d_out;

    // Workspace: Q, K, V fp32 in [b][n][l][e] layout. 3 * 8388608 * 4B = 100.7 MB.
    float* Qf = (float*)d_ws;
    float* Kf = Qf + NM;
    float* Vf = Kf + NM;

    qkv_proj_kernel<<<dim3(128, 48), 256, 0, stream>>>(x, wk, wq, wv, Qf, Kf, Vf);
    attn_kernel<<<dim3(32, 64), 256, 0, stream>>>(Qf, Kf, Vf, out);
}

// Round 3
// 1130.020 us; speedup vs baseline: 4.4316x; 4.4316x over previous
//
#include <hip/hip_runtime.h>
#include <math.h>

#define DIMX   1024
#define NHEADS 16
#define HD     64
#define BATCH  4
#define SEQ    2048
#define NM     (BATCH * NHEADS * SEQ * HD)   // 8388608 elems per Q/K/V tensor

typedef unsigned short ushort_t;
typedef __attribute__((ext_vector_type(8))) short bf16x8;
typedef __attribute__((ext_vector_type(4))) float f32x4;

#define MFMA16(a, b, c) __builtin_amdgcn_mfma_f32_16x16x32_bf16(a, b, c, 0, 0, 0)

// round-to-nearest-even fp32 -> bf16 bits
__device__ __forceinline__ ushort_t f2bf(float x) {
    unsigned u = __float_as_uint(x);
    u += 0x7fffu + ((u >> 16) & 1u);
    return (ushort_t)(u >> 16);
}
__device__ __forceinline__ float bf2f(ushort_t h) {
    return __uint_as_float(((unsigned)h) << 16);
}

// async global->LDS, 16B per lane; LDS base is wave-uniform (HW adds lane*16)
#define GLOAD_LDS16(g, l) \
    __builtin_amdgcn_global_load_lds((const __attribute__((address_space(1))) unsigned int*)(g), \
                                     (__attribute__((address_space(3))) unsigned int*)(l), 16, 0, 0)

// ---------------------------------------------------------------------------
// Kernel 1: QKV projection (fp32 VALU, ~70% of vector roofline).
//  which==1 (Q): fp32 out [bn][l][e]           (attn reads Q once -> fp32 ok)
//  which==0 (K): bf16 hi/lo out [bn][l][e]     (split for 3-pass MFMA QK)
//  which==2 (V): bf16 out TRANSPOSED [bn][e][l] (for contiguous PV B-frags)
// ---------------------------------------------------------------------------
__global__ __launch_bounds__(256) void qkv_proj_kernel(
    const float* __restrict__ x,
    const float* __restrict__ wk,
    const float* __restrict__ wq,
    const float* __restrict__ wv,
    float* __restrict__ Qf, ushort_t* __restrict__ Khi, ushort_t* __restrict__ Klo,
    ushort_t* __restrict__ Vt)
{
    __shared__ float Xs[32][68];   // [k][row]
    __shared__ float Ws[32][68];   // [k][col]

    const int mtile = blockIdx.x;
    const int y     = blockIdx.y;
    const int head  = y & 15;
    const int which = y >> 4;            // 0: wk->K, 1: wq->Q, 2: wv->V
    const float* w = (which == 0) ? wk : (which == 1) ? wq : wv;
    const float* wb = w + (size_t)head * (DIMX * HD);

    const int tid = threadIdx.x;
    const int tr  = tid >> 4;
    const int tc  = tid & 15;
    const int row0 = mtile * 64;

    float acc[4][4] = {{0.f,0.f,0.f,0.f},{0.f,0.f,0.f,0.f},
                       {0.f,0.f,0.f,0.f},{0.f,0.f,0.f,0.f}};

    for (int kc = 0; kc < DIMX; kc += 32) {
        __syncthreads();
        #pragma unroll
        for (int t = 0; t < 8; t++) {
            int i = tid + t * 256;
            int r = i >> 5, c = i & 31;
            Xs[c][r] = x[(size_t)(row0 + r) * DIMX + kc + c];
        }
        #pragma unroll
        for (int t = 0; t < 8; t++) {
            int i = tid + t * 256;
            int r = i >> 6, c = i & 63;
            Ws[r][c] = wb[(size_t)(kc + r) * HD + c];
        }
        __syncthreads();
        if (which != 2) {
            #pragma unroll
            for (int kk = 0; kk < 32; kk++) {
                float4 a = *(const float4*)&Xs[kk][tr * 4];
                float4 b = *(const float4*)&Ws[kk][tc * 4];
                acc[0][0] += a.x*b.x; acc[0][1] += a.x*b.y; acc[0][2] += a.x*b.z; acc[0][3] += a.x*b.w;
                acc[1][0] += a.y*b.x; acc[1][1] += a.y*b.y; acc[1][2] += a.y*b.z; acc[1][3] += a.y*b.w;
                acc[2][0] += a.z*b.x; acc[2][1] += a.z*b.y; acc[2][2] += a.z*b.z; acc[2][3] += a.z*b.w;
                acc[3][0] += a.w*b.x; acc[3][1] += a.w*b.y; acc[3][2] += a.w*b.z; acc[3][3] += a.w*b.w;
            }
        } else {
            // V: compute TRANSPOSED tile: acc[i][j] = Vt[e=tr*4+i][l=row0+tc*4+j]
            #pragma unroll
            for (int kk = 0; kk < 32; kk++) {
                float4 a = *(const float4*)&Ws[kk][tr * 4];   // e-direction
                float4 b = *(const float4*)&Xs[kk][tc * 4];   // l-direction
                acc[0][0] += a.x*b.x; acc[0][1] += a.x*b.y; acc[0][2] += a.x*b.z; acc[0][3] += a.x*b.w;
                acc[1][0] += a.y*b.x; acc[1][1] += a.y*b.y; acc[1][2] += a.y*b.z; acc[1][3] += a.y*b.w;
                acc[2][0] += a.z*b.x; acc[2][1] += a.z*b.y; acc[2][2] += a.z*b.z; acc[2][3] += a.z*b.w;
                acc[3][0] += a.w*b.x; acc[3][1] += a.w*b.y; acc[3][2] += a.w*b.z; acc[3][3] += a.w*b.w;
            }
        }
    }

    if (which == 1) {          // Q: fp32
        #pragma unroll
        for (int i = 0; i < 4; i++) {
            int m = row0 + tr * 4 + i;
            int b = m >> 11, l = m & 2047;
            float4 v = make_float4(acc[i][0], acc[i][1], acc[i][2], acc[i][3]);
            *(float4*)&Qf[(((size_t)b * NHEADS + head) * SEQ + l) * HD + tc * 4] = v;
        }
    } else if (which == 0) {   // K: bf16 hi/lo
        #pragma unroll
        for (int i = 0; i < 4; i++) {
            int m = row0 + tr * 4 + i;
            int b = m >> 11, l = m & 2047;
            size_t base = (((size_t)b * NHEADS + head) * SEQ + l) * HD + tc * 4;
            ushort4 hi, lo;
            hi.x = f2bf(acc[i][0]); lo.x = f2bf(acc[i][0] - bf2f(hi.x));
            hi.y = f2bf(acc[i][1]); lo.y = f2bf(acc[i][1] - bf2f(hi.y));
            hi.z = f2bf(acc[i][2]); lo.z = f2bf(acc[i][2] - bf2f(hi.z));
            hi.w = f2bf(acc[i][3]); lo.w = f2bf(acc[i][3] - bf2f(hi.w));
            *(ushort4*)&Khi[base] = hi;
            *(ushort4*)&Klo[base] = lo;
        }
    } else {                   // V: bf16 transposed [bn][e][l]
        int b = row0 >> 11, l0 = row0 & 2047;
        size_t vbase = ((size_t)b * NHEADS + head) * HD * (size_t)SEQ;
        #pragma unroll
        for (int i = 0; i < 4; i++) {
            int e = tr * 4 + i;
            ushort4 pk;
            pk.x = f2bf(acc[i][0]); pk.y = f2bf(acc[i][1]);
            pk.z = f2bf(acc[i][2]); pk.w = f2bf(acc[i][3]);
            *(ushort4*)&Vt[vbase + (size_t)e * SEQ + l0 + tc * 4] = pk;
        }
    }
}

// ---------------------------------------------------------------------------
// Kernel 2: flash attention with MFMA (split-bf16 QK, bf16 PV).
// Block = 4 waves, 64 q-rows (16/wave). 32 chunks of 64 keys.
// LDS: Khi/Klo [64key][64e] and Vt [64e][64key] bf16 in XOR-swizzled 16B
// granules (granule G holds row r=G>>3, 8-elem block (G&7)^(r&7)) so that
// global_load_lds stays contiguous AND b128 frag reads are bank-conflict-free.
// Softmax state (m,l) lives replicated in registers per quad (C-layout rows).
// ---------------------------------------------------------------------------
__global__ __launch_bounds__(256) void attn_mfma_kernel(
    const float* __restrict__ Qf, const ushort_t* __restrict__ Khi,
    const ushort_t* __restrict__ Klo, const ushort_t* __restrict__ Vt,
    float* __restrict__ out)
{
    __shared__ __align__(16) ushort_t Khs[64 * 64];
    __shared__ __align__(16) ushort_t Kls[64 * 64];
    __shared__ __align__(16) ushort_t Vts[64 * 64];
    __shared__ __align__(16) ushort_t Ps[4 * 16 * 72];   // per-wave P tile, pad 72

    const int qt  = blockIdx.x;       // 0..31
    const int bn  = blockIdx.y;       // 0..63
    const int tid = threadIdx.x;
    const int w    = tid >> 6;
    const int lane = tid & 63;
    const int col  = lane & 15;
    const int quad = lane >> 4;

    const ushort_t* Kh_g = Khi + (size_t)bn * SEQ * HD;
    const ushort_t* Kl_g = Klo + (size_t)bn * SEQ * HD;
    const ushort_t* Vt_g = Vt  + (size_t)bn * HD * SEQ;

    // ---- Q A-fragments in registers: rows = qt*64 + w*16 + col, pre-scaled, split hi/lo
    union { bf16x8 v; short s[8]; } qh[2], ql[2];
    {
        const int qrow = qt * 64 + w * 16 + col;
        const float* qp = Qf + ((size_t)bn * SEQ + qrow) * HD;
        #pragma unroll
        for (int ks = 0; ks < 2; ks++) {
            float qv[8];
            f32x4 a = *(const f32x4*)(qp + ks * 32 + quad * 8);
            f32x4 b = *(const f32x4*)(qp + ks * 32 + quad * 8 + 4);
            qv[0]=a[0]; qv[1]=a[1]; qv[2]=a[2]; qv[3]=a[3];
            qv[4]=b[0]; qv[5]=b[1]; qv[6]=b[2]; qv[7]=b[3];
            #pragma unroll
            for (int j = 0; j < 8; j++) {
                float xsc = qv[j] * 0.125f;              // 1/sqrt(64)
                ushort_t hi = f2bf(xsc);
                ushort_t lo = f2bf(xsc - bf2f(hi));
                qh[ks].s[j] = (short)hi;
                ql[ks].s[j] = (short)lo;
            }
        }
    }

    f32x4 O[4] = {{0,0,0,0},{0,0,0,0},{0,0,0,0},{0,0,0,0}};
    float m_i[4] = {-1e30f, -1e30f, -1e30f, -1e30f};
    float l_i[4] = {0.f, 0.f, 0.f, 0.f};
    ushort_t* Pw = &Ps[w * 16 * 72];

    for (int ch = 0; ch < 32; ch++) {
        __syncthreads();   // previous chunk fully consumed
        // ---- stage K(hi,lo) and V chunk via async global->LDS, swizzled granules
        #pragma unroll
        for (int t = 0; t < 2; t++) {
            int G   = (w * 2 + t) * 64 + lane;          // granule 0..511
            int key = G >> 3;                            // row (key for K, e for V)
            int blk = (G & 7) ^ (key & 7);               // swizzled 8-elem block
            size_t koff = (size_t)(ch * 64 + key) * HD + blk * 8;
            size_t voff = (size_t)key * SEQ + ch * 64 + blk * 8;
            GLOAD_LDS16(Kh_g + koff, Khs + (size_t)(w * 2 + t) * 512);
            GLOAD_LDS16(Kl_g + koff, Kls + (size_t)(w * 2 + t) * 512);
            GLOAD_LDS16(Vt_g + voff, Vts + (size_t)(w * 2 + t) * 512);
        }
        __syncthreads();   // staged data visible

        // ---- S = (Q/8) K^T via 3-pass split-bf16 MFMA. 4 key-tiles of 16.
        f32x4 S[4] = {{0,0,0,0},{0,0,0,0},{0,0,0,0},{0,0,0,0}};
        #pragma unroll
        for (int ks = 0; ks < 2; ks++) {
            #pragma unroll
            for (int t = 0; t < 4; t++) {
                int key = t * 16 + col;
                int g = key * 8 + ((ks * 4 + quad) ^ (key & 7));
                bf16x8 kh = *(const bf16x8*)&Khs[g * 8];
                bf16x8 kl = *(const bf16x8*)&Kls[g * 8];
                S[t] = MFMA16(qh[ks].v, kh, S[t]);
                S[t] = MFMA16(ql[ks].v, kh, S[t]);
                S[t] = MFMA16(qh[ks].v, kl, S[t]);
            }
        }

        // ---- online softmax, all state in registers (rows = quad*4 + r)
        float mnew[4], al[4], ps[4];
        #pragma unroll
        for (int r = 0; r < 4; r++) {
            float mx = fmaxf(fmaxf(S[0][r], S[1][r]), fmaxf(S[2][r], S[3][r]));
            mx = fmaxf(mx, __shfl_xor(mx, 1));
            mx = fmaxf(mx, __shfl_xor(mx, 2));
            mx = fmaxf(mx, __shfl_xor(mx, 4));
            mx = fmaxf(mx, __shfl_xor(mx, 8));
            mnew[r] = fmaxf(m_i[r], mx);
            al[r]   = __expf(m_i[r] - mnew[r]);
            m_i[r]  = mnew[r];
            ps[r]   = 0.f;
        }
        #pragma unroll
        for (int t = 0; t < 4; t++) {
            #pragma unroll
            for (int r = 0; r < 4; r++) {
                float p = __expf(S[t][r] - mnew[r]);
                ps[r] += p;
                Pw[(quad * 4 + r) * 72 + t * 16 + col] = f2bf(p);
            }
        }
        #pragma unroll
        for (int r = 0; r < 4; r++) {
            float s = ps[r];
            s += __shfl_xor(s, 1);
            s += __shfl_xor(s, 2);
            s += __shfl_xor(s, 4);
            s += __shfl_xor(s, 8);
            l_i[r] = l_i[r] * al[r] + s;
            O[0][r] *= al[r]; O[1][r] *= al[r]; O[2][r] *= al[r]; O[3][r] *= al[r];
        }

        // ---- O += P V  (bf16 MFMA; P read back in A-layout from LDS)
        #pragma unroll
        for (int ks = 0; ks < 2; ks++) {
            bf16x8 pf = *(const bf16x8*)&Pw[col * 72 + ks * 32 + quad * 8];
            #pragma unroll
            for (int t = 0; t < 4; t++) {
                int e = t * 16 + col;
                int g = e * 8 + ((ks * 4 + quad) ^ (e & 7));
                bf16x8 vf = *(const bf16x8*)&Vts[g * 8];
                O[t] = MFMA16(pf, vf, O[t]);
            }
        }
    }

    // ---- epilogue: out[b][l][n*64+e] = O / l
    const int b = bn >> 4, n = bn & 15;
    #pragma unroll
    for (int t = 0; t < 4; t++) {
        #pragma unroll
        for (int r = 0; r < 4; r++) {
            int l = qt * 64 + w * 16 + quad * 4 + r;
            out[((size_t)(b * SEQ + l)) * (NHEADS * HD) + n * HD + t * 16 + col] = O[t][r] / l_i[r];
        }
    }
}

// ---------------------------------------------------------------------------
extern "C" void kernel_launch(void* const* d_in, const int* in_sizes, int n_in,
                              void* d_out, int out_size, void* d_ws, size_t ws_size,
                              hipStream_t stream) {
    const float* x  = (const float*)d_in[0];
    const float* wk = (const float*)d_in[1];
    const float* wq = (const float*)d_in[2];
    const float* wv = (const float*)d_in[3];
    float* out = (float*)d_out;

    // ws: Qf fp32 | Khi bf16 | Klo bf16 | Vt bf16(transposed)  = NM*10 B = 84 MB
    float*    Qf  = (float*)d_ws;
    ushort_t* Khi = (ushort_t*)(Qf + NM);
    ushort_t* Klo = Khi + NM;
    ushort_t* Vt  = Klo + NM;

    qkv_proj_kernel<<<dim3(128, 48), 256, 0, stream>>>(x, wk, wq, wv, Qf, Khi, Klo, Vt);
    attn_mfma_kernel<<<dim3(32, 64), 256, 0, stream>>>(Qf, Khi, Klo, Vt, out);
}

// Round 4
// 445.863 us; speedup vs baseline: 11.2317x; 2.5345x over previous
//
#include <hip/hip_runtime.h>
#include <math.h>

#define DIMX   1024
#define NHEADS 16
#define HD     64
#define BATCH  4
#define SEQ    2048
#define NM     (BATCH * NHEADS * SEQ * HD)   // 8388608 elems per Q/K/V tensor

typedef unsigned short ushort_t;
typedef __attribute__((ext_vector_type(8))) short bf16x8;
typedef __attribute__((ext_vector_type(4))) float f32x4;

#define MFMA16(a, b, c) __builtin_amdgcn_mfma_f32_16x16x32_bf16(a, b, c, 0, 0, 0)

// round-to-nearest-even fp32 -> bf16 bits
__device__ __forceinline__ ushort_t f2bf(float x) {
    unsigned u = __float_as_uint(x);
    u += 0x7fffu + ((u >> 16) & 1u);
    return (ushort_t)(u >> 16);
}
__device__ __forceinline__ float bf2f(ushort_t h) {
    return __uint_as_float(((unsigned)h) << 16);
}

// async global->LDS, 16B per lane; LDS base wave-uniform (HW adds lane*16)
#define GLOAD_LDS16(g, l) \
    __builtin_amdgcn_global_load_lds((const __attribute__((address_space(1))) unsigned int*)(g), \
                                     (__attribute__((address_space(3))) unsigned int*)(l), 16, 0, 0)

// ---------------------------------------------------------------------------
// convert_x: split x fp32 -> Xhi, Xlo bf16.  8.4M elems, memory-bound.
// ---------------------------------------------------------------------------
__global__ __launch_bounds__(256) void convert_x(
    const float* __restrict__ x, ushort_t* __restrict__ Xh, ushort_t* __restrict__ Xl)
{
    int i = blockIdx.x * 256 + threadIdx.x;           // f4-slot base
    #pragma unroll
    for (int t = 0; t < 4; t++) {
        int idx = t * 524288 + i;                      // 2048 blocks * 256 * 4 = 2097152 f4
        f32x4 v = ((const f32x4*)x)[idx];
        ushort4 hi, lo;
        hi.x = f2bf(v[0]); lo.x = f2bf(v[0] - bf2f(hi.x));
        hi.y = f2bf(v[1]); lo.y = f2bf(v[1] - bf2f(hi.y));
        hi.z = f2bf(v[2]); lo.z = f2bf(v[2] - bf2f(hi.z));
        hi.w = f2bf(v[3]); lo.w = f2bf(v[3] - bf2f(hi.w));
        ((ushort4*)Xh)[idx] = hi;
        ((ushort4*)Xl)[idx] = lo;
    }
}

// ---------------------------------------------------------------------------
// convert_w: transpose w[n][d][e] -> Wt[e'=n*64+e][d], split hi/lo bf16.
// mat 0 = wq -> Bq rows 0..1023, mat 1 = wk -> rows 1024..2047, mat 2 = wv -> Bvh.
// grid = 3 * 16 heads * 16 d-tiles = 768 blocks; 64x64 tile via LDS.
// ---------------------------------------------------------------------------
__global__ __launch_bounds__(256) void convert_w(
    const float* __restrict__ wk, const float* __restrict__ wq, const float* __restrict__ wv,
    ushort_t* __restrict__ Bqh, ushort_t* __restrict__ Bql, ushort_t* __restrict__ Bvh)
{
    __shared__ float Ts[64][65];
    const int bid = blockIdx.x;
    const int mat = bid >> 8;            // 0..2
    const int rem = bid & 255;
    const int n  = rem >> 4;             // head
    const int dt = rem & 15;             // d-tile
    const float* w = (mat == 0) ? wq : (mat == 1) ? wk : wv;
    const int tid = threadIdx.x;

    #pragma unroll
    for (int t = 0; t < 16; t++) {
        int i = tid + t * 256;
        int r = i >> 6, e = i & 63;
        Ts[r][e] = w[((size_t)n * 1024 + dt * 64 + r) * 64 + e];
    }
    __syncthreads();
    #pragma unroll
    for (int t = 0; t < 16; t++) {
        int i = tid + t * 256;
        int e = i >> 6, r = i & 63;
        float v = Ts[r][e];
        ushort_t hi = f2bf(v);
        size_t o = (size_t)(n * 64 + e) * 1024 + dt * 64 + r;
        if (mat < 2) {
            Bqh[(size_t)mat * 1048576 + o] = hi;
            Bql[(size_t)mat * 1048576 + o] = f2bf(v - bf2f(hi));
        } else {
            Bvh[o] = hi;
        }
    }
}

// ---------------------------------------------------------------------------
// proj_qk: C[8192 m][2048 n'] = X[m][d] * Bqk[n'][d]^T, 3-pass split bf16.
// 128x128 tile, BK=64. LDS rows = 64 bf16 = 128 B = full bank wrap; granule
// swizzle j = g ^ (r&7) -> global_load_lds contiguous + 2-way-max frag reads.
// Epilogue: n' < 1024 -> Qf fp32 [bn][l][e]; else Khi/Klo bf16 [bn][l][e].
// ---------------------------------------------------------------------------
__global__ __launch_bounds__(256) void proj_qk(
    const ushort_t* __restrict__ Xh, const ushort_t* __restrict__ Xl,
    const ushort_t* __restrict__ Bh, const ushort_t* __restrict__ Bl,
    float* __restrict__ Qf, ushort_t* __restrict__ Khi, ushort_t* __restrict__ Klo)
{
    __shared__ __align__(16) ushort_t Ah[128 * 64];
    __shared__ __align__(16) ushort_t Al[128 * 64];
    __shared__ __align__(16) ushort_t Bhs[128 * 64];
    __shared__ __align__(16) ushort_t Bls[128 * 64];

    const int mt = blockIdx.x, nt = blockIdx.y;
    const int tid = threadIdx.x;
    const int w = tid >> 6, lane = tid & 63, col = lane & 15, quad = lane >> 4;
    const int wm = w & 1, wn = w >> 1;

    f32x4 acc[4][4] = {};

    for (int kc = 0; kc < 1024; kc += 64) {
        __syncthreads();
        #pragma unroll
        for (int i = 0; i < 4; i++) {
            int s = (w * 4 + i) * 64 + lane;       // granule slot 0..1023
            int r = s >> 3, j = s & 7, g = j ^ (r & 7);
            size_t aoff = (size_t)(mt * 128 + r) * 1024 + kc + g * 8;
            size_t boff = (size_t)(nt * 128 + r) * 1024 + kc + g * 8;
            GLOAD_LDS16(Xh + aoff, Ah  + (size_t)(w * 4 + i) * 512);
            GLOAD_LDS16(Xl + aoff, Al  + (size_t)(w * 4 + i) * 512);
            GLOAD_LDS16(Bh + boff, Bhs + (size_t)(w * 4 + i) * 512);
            GLOAD_LDS16(Bl + boff, Bls + (size_t)(w * 4 + i) * 512);
        }
        __syncthreads();
        #pragma unroll
        for (int kk = 0; kk < 2; kk++) {
            bf16x8 a_h[4], a_l[4], b_h[4], b_l[4];
            const int gi = kk * 4 + quad;
            #pragma unroll
            for (int t = 0; t < 4; t++) {
                int rA = wm * 64 + t * 16 + col;
                int jA = gi ^ (rA & 7);
                a_h[t] = *(const bf16x8*)&Ah[(rA * 8 + jA) * 8];
                a_l[t] = *(const bf16x8*)&Al[(rA * 8 + jA) * 8];
                int rB = wn * 64 + t * 16 + col;
                int jB = gi ^ (rB & 7);
                b_h[t] = *(const bf16x8*)&Bhs[(rB * 8 + jB) * 8];
                b_l[t] = *(const bf16x8*)&Bls[(rB * 8 + jB) * 8];
            }
            #pragma unroll
            for (int t = 0; t < 4; t++)
                #pragma unroll
                for (int u = 0; u < 4; u++) {
                    acc[t][u] = MFMA16(a_h[t], b_h[u], acc[t][u]);
                    acc[t][u] = MFMA16(a_l[t], b_h[u], acc[t][u]);
                    acc[t][u] = MFMA16(a_h[t], b_l[u], acc[t][u]);
                }
        }
    }

    const bool isQ = (nt < 8);
    #pragma unroll
    for (int t = 0; t < 4; t++) {
        #pragma unroll
        for (int u = 0; u < 4; u++) {
            int np = nt * 128 + wn * 64 + u * 16 + col;    // n' 0..2047
            int head = (np >> 6) & 15, e = np & 63;
            #pragma unroll
            for (int rr = 0; rr < 4; rr++) {
                int mm = mt * 128 + wm * 64 + t * 16 + quad * 4 + rr;
                int bi = mm >> 11, l = mm & 2047;
                size_t base = (((size_t)bi * NHEADS + head) * SEQ + l) * HD + e;
                float v = acc[t][u][rr];
                if (isQ) {
                    Qf[base] = v;
                } else {
                    ushort_t hi = f2bf(v);
                    Khi[base] = hi;
                    Klo[base] = f2bf(v - bf2f(hi));
                }
            }
        }
    }
}

// ---------------------------------------------------------------------------
// proj_v: C[1024 e'][8192 l] = Wvt[e'][d] * X[l][d]^T, 1-pass bf16.
// Operands swapped so C rows are e' -> transposed-V writes are coalesced.
// ---------------------------------------------------------------------------
__global__ __launch_bounds__(256) void proj_v(
    const ushort_t* __restrict__ Wvh, const ushort_t* __restrict__ Xh,
    ushort_t* __restrict__ Vt)
{
    __shared__ __align__(16) ushort_t Ah[128 * 64];
    __shared__ __align__(16) ushort_t Bhs[128 * 64];

    const int mt = blockIdx.x, nt = blockIdx.y;   // mt 0..7 (e'), nt 0..63 (l)
    const int tid = threadIdx.x;
    const int w = tid >> 6, lane = tid & 63, col = lane & 15, quad = lane >> 4;
    const int wm = w & 1, wn = w >> 1;

    f32x4 acc[4][4] = {};

    for (int kc = 0; kc < 1024; kc += 64) {
        __syncthreads();
        #pragma unroll
        for (int i = 0; i < 4; i++) {
            int s = (w * 4 + i) * 64 + lane;
            int r = s >> 3, j = s & 7, g = j ^ (r & 7);
            size_t aoff = (size_t)(mt * 128 + r) * 1024 + kc + g * 8;
            size_t boff = (size_t)(nt * 128 + r) * 1024 + kc + g * 8;
            GLOAD_LDS16(Wvh + aoff, Ah  + (size_t)(w * 4 + i) * 512);
            GLOAD_LDS16(Xh  + boff, Bhs + (size_t)(w * 4 + i) * 512);
        }
        __syncthreads();
        #pragma unroll
        for (int kk = 0; kk < 2; kk++) {
            bf16x8 a_h[4], b_h[4];
            const int gi = kk * 4 + quad;
            #pragma unroll
            for (int t = 0; t < 4; t++) {
                int rA = wm * 64 + t * 16 + col;
                a_h[t] = *(const bf16x8*)&Ah[(rA * 8 + (gi ^ (rA & 7))) * 8];
                int rB = wn * 64 + t * 16 + col;
                b_h[t] = *(const bf16x8*)&Bhs[(rB * 8 + (gi ^ (rB & 7))) * 8];
            }
            #pragma unroll
            for (int t = 0; t < 4; t++)
                #pragma unroll
                for (int u = 0; u < 4; u++)
                    acc[t][u] = MFMA16(a_h[t], b_h[u], acc[t][u]);
        }
    }

    #pragma unroll
    for (int t = 0; t < 4; t++) {
        #pragma unroll
        for (int rr = 0; rr < 4; rr++) {
            int ep = mt * 128 + wm * 64 + t * 16 + quad * 4 + rr;   // e' 0..1023
            int head = ep >> 6, e = ep & 63;
            #pragma unroll
            for (int u = 0; u < 4; u++) {
                int lg = nt * 128 + wn * 64 + u * 16 + col;          // l 0..8191
                int bi = lg >> 11, l = lg & 2047;
                Vt[(((size_t)bi * NHEADS + head) * HD + e) * SEQ + l] = f2bf(acc[t][u][rr]);
            }
        }
    }
}

// ---------------------------------------------------------------------------
// Kernel: flash attention with MFMA (split-bf16 QK, bf16 PV). Unchanged (r3).
// ---------------------------------------------------------------------------
__global__ __launch_bounds__(256) void attn_mfma_kernel(
    const float* __restrict__ Qf, const ushort_t* __restrict__ Khi,
    const ushort_t* __restrict__ Klo, const ushort_t* __restrict__ Vt,
    float* __restrict__ out)
{
    __shared__ __align__(16) ushort_t Khs[64 * 64];
    __shared__ __align__(16) ushort_t Kls[64 * 64];
    __shared__ __align__(16) ushort_t Vts[64 * 64];
    __shared__ __align__(16) ushort_t Ps[4 * 16 * 72];

    const int qt  = blockIdx.x;
    const int bn  = blockIdx.y;
    const int tid = threadIdx.x;
    const int w    = tid >> 6;
    const int lane = tid & 63;
    const int col  = lane & 15;
    const int quad = lane >> 4;

    const ushort_t* Kh_g = Khi + (size_t)bn * SEQ * HD;
    const ushort_t* Kl_g = Klo + (size_t)bn * SEQ * HD;
    const ushort_t* Vt_g = Vt  + (size_t)bn * HD * SEQ;

    union { bf16x8 v; short s[8]; } qh[2], ql[2];
    {
        const int qrow = qt * 64 + w * 16 + col;
        const float* qp = Qf + ((size_t)bn * SEQ + qrow) * HD;
        #pragma unroll
        for (int ks = 0; ks < 2; ks++) {
            float qv[8];
            f32x4 a = *(const f32x4*)(qp + ks * 32 + quad * 8);
            f32x4 b = *(const f32x4*)(qp + ks * 32 + quad * 8 + 4);
            qv[0]=a[0]; qv[1]=a[1]; qv[2]=a[2]; qv[3]=a[3];
            qv[4]=b[0]; qv[5]=b[1]; qv[6]=b[2]; qv[7]=b[3];
            #pragma unroll
            for (int j = 0; j < 8; j++) {
                float xsc = qv[j] * 0.125f;
                ushort_t hi = f2bf(xsc);
                ushort_t lo = f2bf(xsc - bf2f(hi));
                qh[ks].s[j] = (short)hi;
                ql[ks].s[j] = (short)lo;
            }
        }
    }

    f32x4 O[4] = {{0,0,0,0},{0,0,0,0},{0,0,0,0},{0,0,0,0}};
    float m_i[4] = {-1e30f, -1e30f, -1e30f, -1e30f};
    float l_i[4] = {0.f, 0.f, 0.f, 0.f};
    ushort_t* Pw = &Ps[w * 16 * 72];

    for (int ch = 0; ch < 32; ch++) {
        __syncthreads();
        #pragma unroll
        for (int t = 0; t < 2; t++) {
            int G   = (w * 2 + t) * 64 + lane;
            int key = G >> 3;
            int blk = (G & 7) ^ (key & 7);
            size_t koff = (size_t)(ch * 64 + key) * HD + blk * 8;
            size_t voff = (size_t)key * SEQ + ch * 64 + blk * 8;
            GLOAD_LDS16(Kh_g + koff, Khs + (size_t)(w * 2 + t) * 512);
            GLOAD_LDS16(Kl_g + koff, Kls + (size_t)(w * 2 + t) * 512);
            GLOAD_LDS16(Vt_g + voff, Vts + (size_t)(w * 2 + t) * 512);
        }
        __syncthreads();

        f32x4 S[4] = {{0,0,0,0},{0,0,0,0},{0,0,0,0},{0,0,0,0}};
        #pragma unroll
        for (int ks = 0; ks < 2; ks++) {
            #pragma unroll
            for (int t = 0; t < 4; t++) {
                int key = t * 16 + col;
                int g = key * 8 + ((ks * 4 + quad) ^ (key & 7));
                bf16x8 kh = *(const bf16x8*)&Khs[g * 8];
                bf16x8 kl = *(const bf16x8*)&Kls[g * 8];
                S[t] = MFMA16(qh[ks].v, kh, S[t]);
                S[t] = MFMA16(ql[ks].v, kh, S[t]);
                S[t] = MFMA16(qh[ks].v, kl, S[t]);
            }
        }

        float mnew[4], al[4], ps[4];
        #pragma unroll
        for (int r = 0; r < 4; r++) {
            float mx = fmaxf(fmaxf(S[0][r], S[1][r]), fmaxf(S[2][r], S[3][r]));
            mx = fmaxf(mx, __shfl_xor(mx, 1));
            mx = fmaxf(mx, __shfl_xor(mx, 2));
            mx = fmaxf(mx, __shfl_xor(mx, 4));
            mx = fmaxf(mx, __shfl_xor(mx, 8));
            mnew[r] = fmaxf(m_i[r], mx);
            al[r]   = __expf(m_i[r] - mnew[r]);
            m_i[r]  = mnew[r];
            ps[r]   = 0.f;
        }
        #pragma unroll
        for (int t = 0; t < 4; t++) {
            #pragma unroll
            for (int r = 0; r < 4; r++) {
                float p = __expf(S[t][r] - mnew[r]);
                ps[r] += p;
                Pw[(quad * 4 + r) * 72 + t * 16 + col] = f2bf(p);
            }
        }
        #pragma unroll
        for (int r = 0; r < 4; r++) {
            float s = ps[r];
            s += __shfl_xor(s, 1);
            s += __shfl_xor(s, 2);
            s += __shfl_xor(s, 4);
            s += __shfl_xor(s, 8);
            l_i[r] = l_i[r] * al[r] + s;
            O[0][r] *= al[r]; O[1][r] *= al[r]; O[2][r] *= al[r]; O[3][r] *= al[r];
        }

        #pragma unroll
        for (int ks = 0; ks < 2; ks++) {
            bf16x8 pf = *(const bf16x8*)&Pw[col * 72 + ks * 32 + quad * 8];
            #pragma unroll
            for (int t = 0; t < 4; t++) {
                int e = t * 16 + col;
                int g = e * 8 + ((ks * 4 + quad) ^ (e & 7));
                bf16x8 vf = *(const bf16x8*)&Vts[g * 8];
                O[t] = MFMA16(pf, vf, O[t]);
            }
        }
    }

    const int b = bn >> 4, n = bn & 15;
    #pragma unroll
    for (int t = 0; t < 4; t++) {
        #pragma unroll
        for (int r = 0; r < 4; r++) {
            int l = qt * 64 + w * 16 + quad * 4 + r;
            out[((size_t)(b * SEQ + l)) * (NHEADS * HD) + n * HD + t * 16 + col] = O[t][r] / l_i[r];
        }
    }
}

// ---------------------------------------------------------------------------
extern "C" void kernel_launch(void* const* d_in, const int* in_sizes, int n_in,
                              void* d_out, int out_size, void* d_ws, size_t ws_size,
                              hipStream_t stream) {
    const float* x  = (const float*)d_in[0];
    const float* wk = (const float*)d_in[1];
    const float* wq = (const float*)d_in[2];
    const float* wv = (const float*)d_in[3];
    float* out = (float*)d_out;

    // ws layout (111 MB): Xh | Xl (aliased by Vt after proj_qk) | Bqh | Bql | Bvh | Qf | Khi | Klo
    ushort_t* Xh  = (ushort_t*)d_ws;
    ushort_t* Xl  = Xh + NM;
    ushort_t* Vt  = Xl;                      // alias: Xl dead once proj_qk finishes
    ushort_t* Bqh = Xl + NM;                 // [2048][1024]
    ushort_t* Bql = Bqh + 2097152;
    ushort_t* Bvh = Bql + 2097152;           // [1024][1024]
    float*    Qf  = (float*)(Bvh + 1048576);
    ushort_t* Khi = (ushort_t*)(Qf + NM);
    ushort_t* Klo = Khi + NM;

    convert_x<<<2048, 256, 0, stream>>>(x, Xh, Xl);
    convert_w<<<768, 256, 0, stream>>>(wk, wq, wv, Bqh, Bql, Bvh);
    proj_qk<<<dim3(64, 16), 256, 0, stream>>>(Xh, Xl, Bqh, Bql, Qf, Khi, Klo);
    proj_v<<<dim3(8, 64), 256, 0, stream>>>(Bvh, Xh, Vt);
    attn_mfma_kernel<<<dim3(32, 64), 256, 0, stream>>>(Qf, Khi, Klo, Vt, out);
}